// Round 8
// baseline (1154.695 us; speedup 1.0000x reference)
//
#include <hip/hip_runtime.h>
#include <hip/hip_bf16.h>

typedef unsigned short u16;
typedef __bf16 bf16x8 __attribute__((ext_vector_type(8)));
typedef float f32x4 __attribute__((ext_vector_type(4)));
typedef float f32x16 __attribute__((ext_vector_type(16)));
typedef unsigned u32x4 __attribute__((ext_vector_type(4)));
typedef short v2s __attribute__((ext_vector_type(2)));

#define NN 20000
#define NE 320000

// ---------------- ws layout (bytes) ----------------
constexpr size_t SZ_W1  = (size_t)18 * 17 * 512 * 2;  // eW1: K 288, N 544 (32x32 swz)
constexpr size_t SZ_W2  = (size_t)34 * 4  * 512 * 2;  // eW2: K 544, N 128
constexpr size_t SZ_WC1 = (size_t)8  * 8  * 512 * 2;  // cW1: K 128, N 256
constexpr size_t SZ_WC2 = (size_t)16 * 1  * 512 * 2;  // cW2: K 256, N 32(3)
constexpr size_t SZ_WN1 = (size_t)8  * 32 * 512 * 2;  // nW1 (16x16 swz)
constexpr size_t SZ_WN2 = (size_t)16 * 8  * 512 * 2;  // nW2
constexpr size_t OFF_W1   = 0;
constexpr size_t OFF_W2   = OFF_W1 + SZ_W1;
constexpr size_t OFF_WC1  = OFF_W2 + SZ_W2;
constexpr size_t OFF_WC2  = OFF_WC1 + SZ_WC1;
constexpr size_t OFF_WN1  = OFF_WC2 + SZ_WC2;
constexpr size_t OFF_WN2  = OFF_WN1 + SZ_WN1;
constexpr size_t OFF_HB   = OFF_WN2 + SZ_WN2;         // bf16 [NN,128]
constexpr size_t SZ_HB    = (size_t)NN * 128 * 2;
constexpr size_t OFF_AGGH = OFF_HB + SZ_HB;           // bf16 [NN,128]
constexpr size_t SZ_AGGH  = (size_t)NN * 128 * 2;
constexpr size_t OFF_AGGC = OFF_AGGH + SZ_AGGH;       // f32 [NN,9]
constexpr size_t SZ_AGGC  = (size_t)NN * 9 * 4;
constexpr size_t OFF_CNT  = OFF_AGGC + SZ_AGGC;       // f32 [NN]
constexpr size_t SZ_CNT   = (size_t)NN * 4;
constexpr size_t OFF_B1P  = OFF_CNT + SZ_CNT;         // f32 [544] padded eb1
constexpr size_t SZ_B1P   = 544 * 4;

__device__ __forceinline__ u16 f2b(float x) {
  union { float f; unsigned u; } v; v.f = x;
  unsigned r = (v.u + 0x7fffu + ((v.u >> 16) & 1u)) >> 16;
  return (u16)r;
}
__device__ __forceinline__ float b2f(unsigned b) {
  union { unsigned u; float f; } v; v.u = b << 16; return v.f;
}
__device__ __forceinline__ float silu_f(float x) {
  float e = __builtin_amdgcn_exp2f(-1.44269504088896f * x);
  return x * __builtin_amdgcn_rcpf(1.f + e);
}
__device__ __forceinline__ unsigned cvtpk(float a, float b) {
  unsigned d;
  asm("v_cvt_pk_bf16_f32 %0, %1, %2" : "=v"(d) : "v"(a), "v"(b));
  return d;
}
// swap: a.lanes[32:63] <-> b.lanes[0:31]
__device__ __forceinline__ void perm_swap(unsigned &a, unsigned &b) {
  asm("v_permlane32_swap_b32 %0, %1" : "+v"(a), "+v"(b));
}
__device__ __forceinline__ void pk_at(u16* p, unsigned pk) {
#if __has_builtin(__builtin_amdgcn_global_atomic_fadd_v2bf16)
  __builtin_amdgcn_global_atomic_fadd_v2bf16((v2s*)p, __builtin_bit_cast(v2s, pk));
#else
  unsigned* q = (unsigned*)p;
  unsigned old = *q, assumed;
  do {
    assumed = old;
    float lo = b2f(assumed & 0xffffu) + b2f(pk & 0xffffu);
    float hi = b2f(assumed >> 16) + b2f(pk >> 16);
    unsigned nv = (unsigned)f2b(lo) | ((unsigned)f2b(hi) << 16);
    old = atomicCAS(q, assumed, nv);
  } while (old != assumed);
#endif
}
__device__ __forceinline__ f32x16 z16() {
  f32x16 v;
  #pragma unroll
  for (int i = 0; i < 16; i++) v[i] = 0.f;
  return v;
}
__device__ __forceinline__ bf16x8 ldf(const u16* p) {
  return *reinterpret_cast<const bf16x8*>(p);
}
#define MFMA32(A,B,C) __builtin_amdgcn_mfma_f32_32x32x16_bf16((A),(B),(C),0,0,0)

// bias (vector broadcast loads) + silu on a 16-wide 32x32 accumulator
// bp must point at bias + tile*32 + 4*hi (16B aligned)
__device__ __forceinline__ f32x16 bias_silu(const f32x16& a, const float* bp) {
  f32x4 q0 = *(const f32x4*)(bp);
  f32x4 q1 = *(const f32x4*)(bp + 8);
  f32x4 q2 = *(const f32x4*)(bp + 16);
  f32x4 q3 = *(const f32x4*)(bp + 24);
  f32x16 s;
  #pragma unroll
  for (int t = 0; t < 16; t++) {
    float bv = (t < 4) ? q0[t & 3] : (t < 8) ? q1[t & 3] : (t < 12) ? q2[t & 3] : q3[t & 3];
    s[t] = silu_f(a[t] + bv);
  }
  return s;
}

// pack a silu'd D-tile (rows n-local, col=edge=lane) into the two B-frags
// (k-tiles 2t, 2t+1) of the NEXT swapped GEMM, via cvt_pk + permlane32_swap.
__device__ __forceinline__ void pack16(const f32x16& s, bf16x8& fa, bf16x8& fb) {
  unsigned A0 = cvtpk(s[0], s[1]),  A1 = cvtpk(s[2], s[3]);
  unsigned B0 = cvtpk(s[4], s[5]),  B1 = cvtpk(s[6], s[7]);
  unsigned C0 = cvtpk(s[8], s[9]),  C1 = cvtpk(s[10], s[11]);
  unsigned D0 = cvtpk(s[12], s[13]), D1 = cvtpk(s[14], s[15]);
  perm_swap(A0, B0); perm_swap(A1, B1);
  perm_swap(C0, D0); perm_swap(C1, D1);
  u32x4 va = {A0, A1, B0, B1}; fa = __builtin_bit_cast(bf16x8, va);
  u32x4 vb = {C0, C1, D0, D1}; fb = __builtin_bit_cast(bf16x8, vb);
}

// 16x16 B-fragment swizzle (node kernel weights)
__global__ void swz_kernel(const float* __restrict__ W, u16* __restrict__ dst,
                           int Kreal, int Nreal, int KT, int NT) {
  int idx = blockIdx.x * 256 + threadIdx.x;
  int total = KT * NT * 512;
  if (idx >= total) return;
  int e = idx & 7, l = (idx >> 3) & 63, blk = idx >> 9;
  int kt = blk % KT, nt = blk / KT;
  int k = kt * 32 + ((l >> 4) * 8) + e;
  int n = nt * 16 + (l & 15);
  float v = (k < Kreal && n < Nreal) ? W[(size_t)k * Nreal + n] : 0.f;
  dst[idx] = f2b(v);
}

// 32x32 fragment swizzle: dst[((nt*KT+kt)*64+l)*8+e] = W[kt*16+(l>>5)*8+e][nt*32+(l&31)]
__global__ void swz32_kernel(const float* __restrict__ W, u16* __restrict__ dst,
                             int Kreal, int Nreal, int KT, int NT) {
  int idx = blockIdx.x * 256 + threadIdx.x;
  int total = KT * NT * 512;
  if (idx >= total) return;
  int e = idx & 7, l = (idx >> 3) & 63, blk = idx >> 9;
  int kt = blk % KT, nt = blk / KT;
  int k = kt * 16 + ((l >> 5) * 8) + e;
  int n = nt * 32 + (l & 31);
  float v = (k < Kreal && n < Nreal) ? W[(size_t)k * Nreal + n] : 0.f;
  dst[idx] = f2b(v);
}

__global__ void tob16_kernel(const float* __restrict__ x, u16* __restrict__ y, int n) {
  int i = blockIdx.x * 256 + threadIdx.x;
  if (i < n) y[i] = f2b(x[i]);
}

__global__ void padf_kernel(const float* __restrict__ x, float* __restrict__ y,
                            int nreal, int ntot) {
  int i = blockIdx.x * 256 + threadIdx.x;
  if (i < ntot) y[i] = (i < nreal) ? x[i] : 0.f;
}

// ------- barrier-free edge pipeline: 1 wave = 32 edges, swapped-operand MFMA -------
// D[n][edge]: col = edge = lane&31 -> whole edge pipeline is lane-local.
__global__ __launch_bounds__(256, 3)
void edge_kernel(const u16* __restrict__ hb, const int* __restrict__ eidx,
                 const float* __restrict__ coord,
                 const u16* __restrict__ W1s, const float* __restrict__ b1p,
                 const u16* __restrict__ W2s, const float* __restrict__ b2,
                 const u16* __restrict__ WC1s, const float* __restrict__ bc1,
                 const u16* __restrict__ WC2s,
                 u16* __restrict__ agg_h, float* __restrict__ agg_c,
                 float* __restrict__ cnt) {
  const int lane = threadIdx.x & 63;
  const int wv = threadIdx.x >> 6;
  const int l5 = lane & 31;
  const int hi = lane >> 5;
  const int e = (blockIdx.x * 4 + wv) * 32 + l5;   // this lane's edge

  const int r = eidx[e];
  const int c = eidx[NE + e];

  // radial B-frag for GEMM1 k-tile 16 (k 256..271: radial[0..8] + zeros)
  bf16x8 radfrag;
  {
    float cd[9];
    #pragma unroll
    for (int i = 0; i < 9; i++) cd[i] = coord[r * 9 + i] - coord[c * 9 + i];
    u16 rad[9];
    #pragma unroll
    for (int a_ = 0; a_ < 3; a_++)
      #pragma unroll
      for (int b_ = 0; b_ < 3; b_++)
        rad[a_ * 3 + b_] = f2b(cd[a_ * 3] * cd[b_ * 3] + cd[a_ * 3 + 1] * cd[b_ * 3 + 1] +
                               cd[a_ * 3 + 2] * cd[b_ * 3 + 2]);
    unsigned w0_ = hi ? (unsigned)rad[8] : ((unsigned)rad[0] | ((unsigned)rad[1] << 16));
    unsigned w1_ = hi ? 0u : ((unsigned)rad[2] | ((unsigned)rad[3] << 16));
    unsigned w2_ = hi ? 0u : ((unsigned)rad[4] | ((unsigned)rad[5] << 16));
    unsigned w3_ = hi ? 0u : ((unsigned)rad[6] | ((unsigned)rad[7] << 16));
    u32x4 t4 = {w0_, w1_, w2_, w3_};
    radfrag = __builtin_bit_cast(bf16x8, t4);
  }

  const u16* hr = hb + (size_t)r * 128 + hi * 8;   // h[row] k-tiles 0..7
  const u16* hc = hb + (size_t)c * 128 + hi * 8;   // h[col] k-tiles 8..15
  const u16* wlane  = W1s + lane * 8;
  const u16* w2lane = W2s + lane * 8;

  // GEMM2 accumulators: ef-tiles 0..3 (ef = 128), persist across chunks
  f32x16 acc2_[4];
  #pragma unroll
  for (int j = 0; j < 4; j++) acc2_[j] = z16();

  // chunks of 2 GEMM1 n-tiles (t0,t1), then lone tile 16
  for (int ch = 0; ch < 8; ch++) {
    const int t0 = 2 * ch, t1 = t0 + 1;
    f32x16 a0 = z16(), a1 = z16();
    const u16* w0 = wlane + t0 * 18 * 512;
    const u16* w1 = wlane + t1 * 18 * 512;
    #pragma unroll
    for (int kt = 0; kt < 17; kt++) {
      bf16x8 bf;
      if (kt < 8)       bf = ldf(hr + kt * 16);
      else if (kt < 16) bf = ldf(hc + (kt - 8) * 16);
      else              bf = radfrag;
      a0 = MFMA32(ldf(w0 + kt * 512), bf, a0);
      a1 = MFMA32(ldf(w1 + kt * 512), bf, a1);
    }
    // t0 tail: bias+silu -> pack -> GEMM2 partial (k-tiles 2t0, 2t0+1)
    {
      f32x16 s = bias_silu(a0, b1p + t0 * 32 + 4 * hi);
      bf16x8 fa, fb; pack16(s, fa, fb);
      const int kg = 2 * t0;
      #pragma unroll
      for (int j = 0; j < 4; j++) {
        acc2_[j] = MFMA32(ldf(w2lane + (j * 34 + kg) * 512), fa, acc2_[j]);
        acc2_[j] = MFMA32(ldf(w2lane + (j * 34 + kg + 1) * 512), fb, acc2_[j]);
      }
    }
    {
      f32x16 s = bias_silu(a1, b1p + t1 * 32 + 4 * hi);
      bf16x8 fa, fb; pack16(s, fa, fb);
      const int kg = 2 * t1;
      #pragma unroll
      for (int j = 0; j < 4; j++) {
        acc2_[j] = MFMA32(ldf(w2lane + (j * 34 + kg) * 512), fa, acc2_[j]);
        acc2_[j] = MFMA32(ldf(w2lane + (j * 34 + kg + 1) * 512), fb, acc2_[j]);
      }
    }
  }
  {  // tile 16
    f32x16 a0 = z16();
    const u16* w0 = wlane + 16 * 18 * 512;
    #pragma unroll
    for (int kt = 0; kt < 17; kt++) {
      bf16x8 bf;
      if (kt < 8)       bf = ldf(hr + kt * 16);
      else if (kt < 16) bf = ldf(hc + (kt - 8) * 16);
      else              bf = radfrag;
      a0 = MFMA32(ldf(w0 + kt * 512), bf, a0);
    }
    f32x16 s = bias_silu(a0, b1p + 16 * 32 + 4 * hi);
    bf16x8 fa, fb; pack16(s, fa, fb);
    #pragma unroll
    for (int j = 0; j < 4; j++) {
      acc2_[j] = MFMA32(ldf(w2lane + (j * 34 + 32) * 512), fa, acc2_[j]);
      acc2_[j] = MFMA32(ldf(w2lane + (j * 34 + 33) * 512), fb, acc2_[j]);
    }
  }

  // ef = silu(acc2 + b2): atomics (packed payload reused) + B-frags for GEMM3
  bf16x8 eff[8];
  u16* ap = agg_h + (size_t)r * 128 + hi * 4;
  #pragma unroll
  for (int j = 0; j < 4; j++) {
    f32x16 s = bias_silu(acc2_[j], b2 + j * 32 + 4 * hi);
    unsigned A0 = cvtpk(s[0], s[1]),  A1 = cvtpk(s[2], s[3]);
    unsigned B0 = cvtpk(s[4], s[5]),  B1 = cvtpk(s[6], s[7]);
    unsigned C0 = cvtpk(s[8], s[9]),  C1 = cvtpk(s[10], s[11]);
    unsigned D0 = cvtpk(s[12], s[13]), D1 = cvtpk(s[14], s[15]);
    u16* aj = ap + j * 32;
    pk_at(aj + 0,  A0); pk_at(aj + 2,  A1);
    pk_at(aj + 8,  B0); pk_at(aj + 10, B1);
    pk_at(aj + 16, C0); pk_at(aj + 18, C1);
    pk_at(aj + 24, D0); pk_at(aj + 26, D1);
    perm_swap(A0, B0); perm_swap(A1, B1);
    perm_swap(C0, D0); perm_swap(C1, D1);
    u32x4 va = {A0, A1, B0, B1}; eff[2 * j]     = __builtin_bit_cast(bf16x8, va);
    u32x4 vb = {C0, C1, D0, D1}; eff[2 * j + 1] = __builtin_bit_cast(bf16x8, vb);
  }

  // GEMM3 (chunks of 2 WC1 n-tiles) -> silu -> pack -> GEMM4 accumulate
  const u16* wc1lane = WC1s + lane * 8;
  const u16* wc2lane = WC2s + lane * 8;
  f32x16 a4 = z16();
  #pragma unroll
  for (int g = 0; g < 4; g++) {
    f32x16 ca = z16(), cb = z16();
    const u16* wa = wc1lane + (2 * g) * 8 * 512;
    const u16* wb = wa + 8 * 512;
    #pragma unroll
    for (int kt = 0; kt < 8; kt++) {
      ca = MFMA32(ldf(wa + kt * 512), eff[kt], ca);
      cb = MFMA32(ldf(wb + kt * 512), eff[kt], cb);
    }
    {
      f32x16 s = bias_silu(ca, bc1 + (2 * g) * 32 + 4 * hi);
      bf16x8 fa, fb; pack16(s, fa, fb);
      a4 = MFMA32(ldf(wc2lane + (4 * g) * 512), fa, a4);
      a4 = MFMA32(ldf(wc2lane + (4 * g + 1) * 512), fb, a4);
    }
    {
      f32x16 s = bias_silu(cb, bc1 + (2 * g + 1) * 32 + 4 * hi);
      bf16x8 fa, fb; pack16(s, fa, fb);
      a4 = MFMA32(ldf(wc2lane + (4 * g + 2) * 512), fa, a4);
      a4 = MFMA32(ldf(wc2lane + (4 * g + 3) * 512), fb, a4);
    }
  }

  // phi rows 0..2 live in hi=0 lanes (r=0,1,2); agg_c / cnt atomics
  if (hi == 0) {
    const float p0 = a4[0], p1 = a4[1], p2 = a4[2];
    float cd[9];
    #pragma unroll
    for (int i = 0; i < 9; i++) cd[i] = coord[r * 9 + i] - coord[c * 9 + i];
    float* gc = agg_c + (size_t)r * 9;
    #pragma unroll
    for (int d = 0; d < 3; d++) {
      atomicAdd(gc + d,     cd[d]     * p0);
      atomicAdd(gc + 3 + d, cd[3 + d] * p1);
      atomicAdd(gc + 6 + d, cd[6 + d] * p2);
    }
    atomicAdd(cnt + r, 1.f);
  }
}

// ---------------- node MLP (16x16 path; agg_h bf16) ----------------
__global__ __launch_bounds__(512)
void node_kernel(const float* __restrict__ h, const u16* __restrict__ hb,
                 const u16* __restrict__ aggh,
                 const u16* __restrict__ WN1s, const float* __restrict__ nb1,
                 const u16* __restrict__ WN2s, const float* __restrict__ nb2,
                 float* __restrict__ out) {
  __shared__ __align__(16) u16 buf[64 * 520];
  const int tid = threadIdx.x;
  const int lane = tid & 63;
  const int w = tid >> 6;
  const int l_lo = lane & 15;
  const int l_hi = lane >> 4;
  const int n0 = blockIdx.x << 6;

  for (int q = tid; q < 2048; q += 512) {
    const int e = q >> 5, sub = q & 31, which = sub >> 4, j = sub & 15;
    const int row = n0 + e;
    const u16* src = which ? aggh : hb;
    int4 v;
    if (row < NN) v = *reinterpret_cast<const int4*>(src + (size_t)row * 128 + j * 8);
    else { v.x = v.y = v.z = v.w = 0; }
    *reinterpret_cast<int4*>(buf + e * 264 + which * 128 + j * 8) = v;
  }
  __syncthreads();

  f32x4 acc[4][4];
  #pragma unroll
  for (int i = 0; i < 4; i++)
    #pragma unroll
    for (int m = 0; m < 4; m++) acc[i][m] = {0.f, 0.f, 0.f, 0.f};
  for (int kt = 0; kt < 8; kt++) {
    bf16x8 af[4];
    #pragma unroll
    for (int m = 0; m < 4; m++)
      af[m] = *reinterpret_cast<const bf16x8*>(buf + (m * 16 + l_lo) * 264 + kt * 32 + l_hi * 8);
    #pragma unroll
    for (int i = 0; i < 4; i++) {
      const int nt = w + 8 * i;
      const bf16x8 bfr = *reinterpret_cast<const bf16x8*>(WN1s + (((nt * 8 + kt) << 6) + lane) * 8);
      #pragma unroll
      for (int m = 0; m < 4; m++)
        acc[i][m] = __builtin_amdgcn_mfma_f32_16x16x32_bf16(af[m], bfr, acc[i][m], 0, 0, 0);
    }
  }
  __syncthreads();
  #pragma unroll
  for (int i = 0; i < 4; i++) {
    const int nt = w + 8 * i;
    const int coln = nt * 16 + l_lo;
    const float bias = nb1[coln];
    #pragma unroll
    for (int m = 0; m < 4; m++)
      #pragma unroll
      for (int rr = 0; rr < 4; rr++) {
        const int row = m * 16 + l_hi * 4 + rr;
        buf[row * 520 + coln] = f2b(silu_f(acc[i][m][rr] + bias));
      }
  }
  __syncthreads();

  f32x4 acc2[4];
  #pragma unroll
  for (int m = 0; m < 4; m++) acc2[m] = {0.f, 0.f, 0.f, 0.f};
  for (int kt = 0; kt < 16; kt++) {
    const bf16x8 bfr = *reinterpret_cast<const bf16x8*>(WN2s + (((w * 16 + kt) << 6) + lane) * 8);
    #pragma unroll
    for (int m = 0; m < 4; m++) {
      const bf16x8 af = *reinterpret_cast<const bf16x8*>(buf + (m * 16 + l_lo) * 520 + kt * 32 + l_hi * 8);
      acc2[m] = __builtin_amdgcn_mfma_f32_16x16x32_bf16(af, bfr, acc2[m], 0, 0, 0);
    }
  }
  {
    const int coln = w * 16 + l_lo;
    const float bias = nb2[coln];
    #pragma unroll
    for (int m = 0; m < 4; m++)
      #pragma unroll
      for (int rr = 0; rr < 4; rr++) {
        const int row = n0 + m * 16 + l_hi * 4 + rr;
        if (row < NN)
          out[(size_t)row * 128 + coln] = h[(size_t)row * 128 + coln] + silu_f(acc2[m][rr] + bias);
      }
  }
}

__global__ void coord_kernel(const float* __restrict__ coord, const float* __restrict__ agg_c,
                             const float* __restrict__ cnt, float* __restrict__ out) {
  int i = blockIdx.x * 256 + threadIdx.x;
  if (i < NN * 9) {
    float cc = fmaxf(cnt[i / 9], 1.f);
    float v = agg_c[i] / cc;
    v = fminf(fmaxf(v, -10.f), 10.f);
    out[i] = coord[i] + v;
  }
}

extern "C" void kernel_launch(void* const* d_in, const int* in_sizes, int n_in,
                              void* d_out, int out_size, void* d_ws, size_t ws_size,
                              hipStream_t stream) {
  (void)in_sizes; (void)n_in; (void)out_size; (void)ws_size;
  const float* h     = (const float*)d_in[0];
  const int*   eidx  = (const int*)d_in[1];
  const float* coord = (const float*)d_in[2];
  const float* eW1 = (const float*)d_in[3];  const float* eb1 = (const float*)d_in[4];
  const float* eW2 = (const float*)d_in[5];  const float* eb2 = (const float*)d_in[6];
  const float* nW1 = (const float*)d_in[7];  const float* nb1 = (const float*)d_in[8];
  const float* nW2 = (const float*)d_in[9];  const float* nb2 = (const float*)d_in[10];
  const float* cW1 = (const float*)d_in[11]; const float* cb1 = (const float*)d_in[12];
  const float* cW2 = (const float*)d_in[13];

  char* ws = (char*)d_ws;
  u16* W1s  = (u16*)(ws + OFF_W1);
  u16* W2s  = (u16*)(ws + OFF_W2);
  u16* WC1s = (u16*)(ws + OFF_WC1);
  u16* WC2s = (u16*)(ws + OFF_WC2);
  u16* WN1s = (u16*)(ws + OFF_WN1);
  u16* WN2s = (u16*)(ws + OFF_WN2);
  u16* hb   = (u16*)(ws + OFF_HB);
  u16* agg_h  = (u16*)(ws + OFF_AGGH);
  float* agg_c = (float*)(ws + OFF_AGGC);
  float* cnt   = (float*)(ws + OFF_CNT);
  float* b1p   = (float*)(ws + OFF_B1P);
  float* out   = (float*)d_out;

  hipMemsetAsync(ws + OFF_AGGH, 0, SZ_AGGH + SZ_AGGC + SZ_CNT, stream);

  swz32_kernel<<<18 * 17 * 2, 256, 0, stream>>>(eW1, W1s, 265, 530, 18, 17);
  swz32_kernel<<<34 * 4 * 2, 256, 0, stream>>>(eW2, W2s, 530, 128, 34, 4);
  swz32_kernel<<<8 * 8 * 2, 256, 0, stream>>>(cW1, WC1s, 128, 256, 8, 8);
  swz32_kernel<<<16 * 1 * 2, 256, 0, stream>>>(cW2, WC2s, 256, 3, 16, 1);
  swz_kernel<<<8 * 32 * 2, 256, 0, stream>>>(nW1, WN1s, 256, 512, 8, 32);
  swz_kernel<<<16 * 8 * 2, 256, 0, stream>>>(nW2, WN2s, 512, 128, 16, 8);
  tob16_kernel<<<(NN * 128 + 255) / 256, 256, 0, stream>>>(h, hb, NN * 128);
  padf_kernel<<<3, 256, 0, stream>>>(eb1, b1p, 530, 544);

  edge_kernel<<<NE / 128, 256, 0, stream>>>(hb, eidx, coord, W1s, b1p, W2s, eb2,
                                            WC1s, cb1, WC2s, agg_h, agg_c, cnt);
  node_kernel<<<(NN + 63) / 64, 512, 0, stream>>>(h, hb, agg_h, WN1s, nb1, WN2s, nb2, out);
  coord_kernel<<<(NN * 9 + 255) / 256, 256, 0, stream>>>(coord, agg_c, cnt, out + (size_t)NN * 128);
}

// Round 9
// 458.414 us; speedup vs baseline: 2.5189x; 2.5189x over previous
//
#include <hip/hip_runtime.h>
#include <hip/hip_bf16.h>

typedef unsigned short u16;
typedef __bf16 bf16x8 __attribute__((ext_vector_type(8)));
typedef float f32x4 __attribute__((ext_vector_type(4)));
typedef float f32x16 __attribute__((ext_vector_type(16)));
typedef short v2s __attribute__((ext_vector_type(2)));

#define NN 20000
#define NE 320000

// ---------------- ws layout (bytes) ----------------
constexpr size_t SZ_W1  = (size_t)18 * 17 * 512 * 2;  // eW1: K 288, N 544 (32x32 swz)
constexpr size_t SZ_W2  = (size_t)34 * 4  * 512 * 2;  // eW2: K 544, N 128
constexpr size_t SZ_WC1 = (size_t)8  * 8  * 512 * 2;  // cW1: K 128, N 256
constexpr size_t SZ_WC2 = (size_t)16 * 1  * 512 * 2;  // cW2: K 256, N 32(3)
constexpr size_t SZ_WN1 = (size_t)8  * 32 * 512 * 2;  // nW1 (16x16 swz)
constexpr size_t SZ_WN2 = (size_t)16 * 8  * 512 * 2;  // nW2
constexpr size_t OFF_W1   = 0;
constexpr size_t OFF_W2   = OFF_W1 + SZ_W1;
constexpr size_t OFF_WC1  = OFF_W2 + SZ_W2;
constexpr size_t OFF_WC2  = OFF_WC1 + SZ_WC1;
constexpr size_t OFF_WN1  = OFF_WC2 + SZ_WC2;
constexpr size_t OFF_WN2  = OFF_WN1 + SZ_WN1;
constexpr size_t OFF_HB   = OFF_WN2 + SZ_WN2;         // bf16 [NN,128]
constexpr size_t SZ_HB    = (size_t)NN * 128 * 2;
constexpr size_t OFF_AGGH = OFF_HB + SZ_HB;           // bf16 [NN,128]
constexpr size_t SZ_AGGH  = (size_t)NN * 128 * 2;
constexpr size_t OFF_AGGC = OFF_AGGH + SZ_AGGH;       // f32 [NN,9]
constexpr size_t SZ_AGGC  = (size_t)NN * 9 * 4;
constexpr size_t OFF_CNT  = OFF_AGGC + SZ_AGGC;       // f32 [NN]
constexpr size_t SZ_CNT   = (size_t)NN * 4;

__device__ __forceinline__ u16 f2b(float x) {
  union { float f; unsigned u; } v; v.f = x;
  unsigned r = (v.u + 0x7fffu + ((v.u >> 16) & 1u)) >> 16;
  return (u16)r;
}
__device__ __forceinline__ float b2f(unsigned b) {
  union { unsigned u; float f; } v; v.u = b << 16; return v.f;
}
__device__ __forceinline__ float silu_f(float x) {
  float e = __builtin_amdgcn_exp2f(-1.44269504088896f * x);
  return x * __builtin_amdgcn_rcpf(1.f + e);
}
__device__ __forceinline__ void pk_atomic_bf16(u16* p, float a, float b) {
#if __has_builtin(__builtin_amdgcn_global_atomic_fadd_v2bf16)
  v2s v; v[0] = (short)f2b(a); v[1] = (short)f2b(b);
  __builtin_amdgcn_global_atomic_fadd_v2bf16((v2s*)p, v);
#else
  unsigned* q = (unsigned*)p;
  unsigned old = *q, assumed;
  do {
    assumed = old;
    float lo = b2f(assumed & 0xffffu) + a;
    float hi = b2f(assumed >> 16) + b;
    unsigned nv = (unsigned)f2b(lo) | ((unsigned)f2b(hi) << 16);
    old = atomicCAS(q, assumed, nv);
  } while (old != assumed);
#endif
}
__device__ __forceinline__ f32x16 z16() {
  f32x16 v;
  #pragma unroll
  for (int i = 0; i < 16; i++) v[i] = 0.f;
  return v;
}
__device__ __forceinline__ bf16x8 ldf(const u16* p) {
  return *reinterpret_cast<const bf16x8*>(p);
}
#define MFMA32(A,B,C) __builtin_amdgcn_mfma_f32_32x32x16_bf16((A),(B),(C),0,0,0)

// 16x16 B-fragment swizzle (node kernel weights)
__global__ void swz_kernel(const float* __restrict__ W, u16* __restrict__ dst,
                           int Kreal, int Nreal, int KT, int NT) {
  int idx = blockIdx.x * 256 + threadIdx.x;
  int total = KT * NT * 512;
  if (idx >= total) return;
  int e = idx & 7, l = (idx >> 3) & 63, blk = idx >> 9;
  int kt = blk % KT, nt = blk / KT;
  int k = kt * 32 + ((l >> 4) * 8) + e;
  int n = nt * 16 + (l & 15);
  float v = (k < Kreal && n < Nreal) ? W[(size_t)k * Nreal + n] : 0.f;
  dst[idx] = f2b(v);
}

// 32x32 B-fragment swizzle
__global__ void swz32_kernel(const float* __restrict__ W, u16* __restrict__ dst,
                             int Kreal, int Nreal, int KT, int NT) {
  int idx = blockIdx.x * 256 + threadIdx.x;
  int total = KT * NT * 512;
  if (idx >= total) return;
  int e = idx & 7, l = (idx >> 3) & 63, blk = idx >> 9;
  int kt = blk % KT, nt = blk / KT;
  int k = kt * 16 + ((l >> 5) * 8) + e;
  int n = nt * 32 + (l & 31);
  float v = (k < Kreal && n < Nreal) ? W[(size_t)k * Nreal + n] : 0.f;
  dst[idx] = f2b(v);
}

__global__ void tob16_kernel(const float* __restrict__ x, u16* __restrict__ y, int n) {
  int i = blockIdx.x * 256 + threadIdx.x;
  if (i < n) y[i] = f2b(x[i]);
}

// -------- edge pipeline: M=64, 4 waves, 2 m-tiles/wave, dbuf Y1, 8 barriers --------
__global__ __launch_bounds__(256, 4)
void edge_kernel(const u16* __restrict__ hb, const int* __restrict__ eidx,
                 const float* __restrict__ coord,
                 const u16* __restrict__ W1s, const float* __restrict__ b1,
                 const u16* __restrict__ W2s, const float* __restrict__ b2,
                 const u16* __restrict__ WC1s, const float* __restrict__ bc1,
                 const u16* __restrict__ WC2s,
                 u16* __restrict__ agg_h, float* __restrict__ agg_c,
                 float* __restrict__ cnt) {
  __shared__ __align__(16) u16 bufA[64 * 296];      // A1 [64][288+8] -> Y3 [64][264]
  __shared__ __align__(16) u16 bufB[2][64 * 136];   // Y1 chunk dbuf; bufB[1] later = ef
  __shared__ float phi_s[64][4];
  __shared__ int row_s[64];

  const int tid = threadIdx.x;
  const int lane = tid & 63;
  const int nh = tid >> 6;       // wave id = n-group
  const int l5 = lane & 31;
  const int hi = lane >> 5;
  const int e0 = blockIdx.x << 6;

  // gather h (2048 int4) + radial (tid<64)
  for (int q = tid; q < 2048; q += 256) {
    const int e = q >> 5, sub = q & 31, which = sub >> 4, j = sub & 15;
    const int node = eidx[(which ? NE : 0) + e0 + e];
    const int4 v = *reinterpret_cast<const int4*>(hb + (size_t)node * 128 + j * 8);
    *reinterpret_cast<int4*>(bufA + e * 296 + which * 128 + j * 8) = v;
  }
  if (tid < 64) {
    const int r = eidx[e0 + tid], c = eidx[NE + e0 + tid];
    row_s[tid] = r;
    float cd[9];
    #pragma unroll
    for (int i = 0; i < 9; i++) cd[i] = coord[r * 9 + i] - coord[c * 9 + i];
    u16* arow = bufA + tid * 296;
    #pragma unroll
    for (int a = 0; a < 3; a++)
      #pragma unroll
      for (int b = 0; b < 3; b++) {
        float rad = cd[a*3]*cd[b*3] + cd[a*3+1]*cd[b*3+1] + cd[a*3+2]*cd[b*3+2];
        arow[256 + a * 3 + b] = f2b(rad);
      }
    #pragma unroll
    for (int k = 265; k < 288; k++) arow[k] = (u16)0;
  }
  __syncthreads();  // b0: A1 + row_s ready

  // ---- chunked GEMM1 [64,288]x[288,544] -> silu -> GEMM2 [64,544]x[544,128] ----
  // chunk c: GEMM1 n-tile nt = c*4 + nh (<17); one barrier per chunk (write->read);
  // write(c+1) goes to the other bufB half, so no read-side barrier needed.
  f32x16 acc2[2];
  #pragma unroll
  for (int m = 0; m < 2; m++) acc2[m] = z16();

  for (int c = 0; c < 5; c++) {
    const int nt = c * 4 + nh;
    const bool act = (nt < 17);
    f32x16 acc1[2];
    #pragma unroll
    for (int m = 0; m < 2; m++) acc1[m] = z16();

    if (act) {
      const u16* wp = W1s + (((nt * 18) << 6) + lane) * 8;
      for (int kt = 0; kt < 18; kt++) {
        const bf16x8 bw = ldf(wp + kt * 512);
        const bf16x8 a0 = ldf(bufA + l5 * 296 + kt * 16 + hi * 8);
        const bf16x8 a1 = ldf(bufA + (32 + l5) * 296 + kt * 16 + hi * 8);
        acc1[0] = MFMA32(a0, bw, acc1[0]);
        acc1[1] = MFMA32(a1, bw, acc1[1]);
      }
    }
    u16* bw_dst = bufB[c & 1];
    if (act) {
      const int colg = nt * 32 + l5;
      const float bias = (colg < 530) ? b1[colg] : 0.f;
      const int coll = nh * 32 + l5;
      #pragma unroll
      for (int m = 0; m < 2; m++)
        #pragma unroll
        for (int r = 0; r < 16; r++) {
          const int rowi = m * 32 + ((r & 3) + 8 * (r >> 2) + 4 * hi);
          bw_dst[rowi * 136 + coll] = f2b(silu_f(acc1[m][r] + bias));
        }
    }
    __syncthreads();  // Y1 chunk ready (also separates next write from old reads)
    const int nk2 = (c < 4) ? 8 : 2;
    const u16* wp2 = W2s + (((nh * 34 + c * 8) << 6) + lane) * 8;
    const u16* bsrc = bufB[c & 1];
    for (int k2 = 0; k2 < nk2; k2++) {
      const bf16x8 bw = ldf(wp2 + k2 * 512);
      const bf16x8 a0 = ldf(bsrc + l5 * 136 + k2 * 16 + hi * 8);
      const bf16x8 a1 = ldf(bsrc + (32 + l5) * 136 + k2 * 16 + hi * 8);
      acc2[0] = MFMA32(a0, bw, acc2[0]);
      acc2[1] = MFMA32(a1, bw, acc2[1]);
    }
  }

  // ef = silu(acc2 + b2) -> bufB[1] [64][136] + coalesced pk atomics
  // (safe: all waves' last reads of bufB[1] were chunk 3, before barrier of chunk 4)
  {
    const int col = nh * 32 + l5;
    const float bias = b2[col];
    #pragma unroll
    for (int m = 0; m < 2; m++)
      #pragma unroll
      for (int r = 0; r < 16; r++) {
        const int rowi = m * 32 + ((r & 3) + 8 * (r >> 2) + 4 * hi);
        const float ef = silu_f(acc2[m][r] + bias);
        bufB[1][rowi * 136 + col] = f2b(ef);
        const float other = __shfl_xor(ef, 1);
        if ((l5 & 1) == 0)
          pk_atomic_bf16(agg_h + (size_t)row_s[rowi] * 128 + col, ef, other);
      }
  }
  __syncthreads();  // b6: ef ready

  // GEMM3: ef[64,128] x WC1[128,256]; wave: 2 m-tiles x n-tiles nh*2+{0,1}
  f32x16 acc3[2][2];
  #pragma unroll
  for (int i = 0; i < 2; i++)
    #pragma unroll
    for (int m = 0; m < 2; m++) acc3[i][m] = z16();
  {
    const u16* wpa = WC1s + ((((nh * 2) * 8) << 6) + lane) * 8;
    const u16* wpb = wpa + 8 * 512;
    for (int kt = 0; kt < 8; kt++) {
      const bf16x8 a0 = ldf(bufB[1] + l5 * 136 + kt * 16 + hi * 8);
      const bf16x8 a1 = ldf(bufB[1] + (32 + l5) * 136 + kt * 16 + hi * 8);
      const bf16x8 w0 = ldf(wpa + kt * 512);
      const bf16x8 w1 = ldf(wpb + kt * 512);
      acc3[0][0] = MFMA32(a0, w0, acc3[0][0]);
      acc3[0][1] = MFMA32(a1, w0, acc3[0][1]);
      acc3[1][0] = MFMA32(a0, w1, acc3[1][0]);
      acc3[1][1] = MFMA32(a1, w1, acc3[1][1]);
    }
  }
  // epi3 -> bufA as Y3 [64][264] (A1 fully consumed: all waves past chunk-4 barrier)
  #pragma unroll
  for (int i = 0; i < 2; i++) {
    const int col = (nh * 2 + i) * 32 + l5;
    const float bias = bc1[col];
    #pragma unroll
    for (int m = 0; m < 2; m++)
      #pragma unroll
      for (int r = 0; r < 16; r++) {
        const int rowi = m * 32 + ((r & 3) + 8 * (r >> 2) + 4 * hi);
        bufA[rowi * 264 + col] = f2b(silu_f(acc3[i][m][r] + bias));
      }
  }
  __syncthreads();  // b7: Y3 ready (waves 2,3 exit after this)

  // GEMM4 (waves 0,1): m-tile = nh; Y3[64,256] x WC2[256,32(3)]
  if (nh < 2) {
    f32x16 acc4 = z16();
    const u16* wp4 = WC2s + lane * 8;
    for (int kt = 0; kt < 16; kt++) {
      const bf16x8 a = ldf(bufA + (nh * 32 + l5) * 264 + kt * 16 + hi * 8);
      const bf16x8 bw = ldf(wp4 + kt * 512);
      acc4 = MFMA32(a, bw, acc4);
    }
    if (l5 < 3) {
      #pragma unroll
      for (int r = 0; r < 16; r++)
        phi_s[nh * 32 + ((r & 3) + 8 * (r >> 2) + 4 * hi)][l5] = acc4[r];
    }
    // wave-internal LDS handoff (lgkmcnt inserted by compiler)
    if (lane < 32) {
      const int el = nh * 32 + lane;
      const int r = row_s[el], ci = eidx[NE + e0 + el];
      float cd[9];
      #pragma unroll
      for (int i = 0; i < 9; i++) cd[i] = coord[r * 9 + i] - coord[ci * 9 + i];
      const float p0 = phi_s[el][0], p1 = phi_s[el][1], p2 = phi_s[el][2];
      float* gc = agg_c + (size_t)r * 9;
      #pragma unroll
      for (int d = 0; d < 3; d++) {
        atomicAdd(gc + d,     cd[d]     * p0);
        atomicAdd(gc + 3 + d, cd[3 + d] * p1);
        atomicAdd(gc + 6 + d, cd[6 + d] * p2);
      }
      atomicAdd(cnt + r, 1.f);
    }
  }
}

// ---------------- node MLP (16x16 path; agg_h bf16) ----------------
__global__ __launch_bounds__(512)
void node_kernel(const float* __restrict__ h, const u16* __restrict__ hb,
                 const u16* __restrict__ aggh,
                 const u16* __restrict__ WN1s, const float* __restrict__ nb1,
                 const u16* __restrict__ WN2s, const float* __restrict__ nb2,
                 float* __restrict__ out) {
  __shared__ __align__(16) u16 buf[64 * 520];
  const int tid = threadIdx.x;
  const int lane = tid & 63;
  const int w = tid >> 6;
  const int l_lo = lane & 15;
  const int l_hi = lane >> 4;
  const int n0 = blockIdx.x << 6;

  for (int q = tid; q < 2048; q += 512) {
    const int e = q >> 5, sub = q & 31, which = sub >> 4, j = sub & 15;
    const int row = n0 + e;
    const u16* src = which ? aggh : hb;
    int4 v;
    if (row < NN) v = *reinterpret_cast<const int4*>(src + (size_t)row * 128 + j * 8);
    else { v.x = v.y = v.z = v.w = 0; }
    *reinterpret_cast<int4*>(buf + e * 264 + which * 128 + j * 8) = v;
  }
  __syncthreads();

  f32x4 acc[4][4];
  #pragma unroll
  for (int i = 0; i < 4; i++)
    #pragma unroll
    for (int m = 0; m < 4; m++) acc[i][m] = {0.f, 0.f, 0.f, 0.f};
  for (int kt = 0; kt < 8; kt++) {
    bf16x8 af[4];
    #pragma unroll
    for (int m = 0; m < 4; m++)
      af[m] = *reinterpret_cast<const bf16x8*>(buf + (m * 16 + l_lo) * 264 + kt * 32 + l_hi * 8);
    #pragma unroll
    for (int i = 0; i < 4; i++) {
      const int nt = w + 8 * i;
      const bf16x8 bfr = *reinterpret_cast<const bf16x8*>(WN1s + (((nt * 8 + kt) << 6) + lane) * 8);
      #pragma unroll
      for (int m = 0; m < 4; m++)
        acc[i][m] = __builtin_amdgcn_mfma_f32_16x16x32_bf16(af[m], bfr, acc[i][m], 0, 0, 0);
    }
  }
  __syncthreads();
  #pragma unroll
  for (int i = 0; i < 4; i++) {
    const int nt = w + 8 * i;
    const int coln = nt * 16 + l_lo;
    const float bias = nb1[coln];
    #pragma unroll
    for (int m = 0; m < 4; m++)
      #pragma unroll
      for (int rr = 0; rr < 4; rr++) {
        const int row = m * 16 + l_hi * 4 + rr;
        buf[row * 520 + coln] = f2b(silu_f(acc[i][m][rr] + bias));
      }
  }
  __syncthreads();

  f32x4 acc2[4];
  #pragma unroll
  for (int m = 0; m < 4; m++) acc2[m] = {0.f, 0.f, 0.f, 0.f};
  for (int kt = 0; kt < 16; kt++) {
    const bf16x8 bfr = *reinterpret_cast<const bf16x8*>(WN2s + (((w * 16 + kt) << 6) + lane) * 8);
    #pragma unroll
    for (int m = 0; m < 4; m++) {
      const bf16x8 af = *reinterpret_cast<const bf16x8*>(buf + (m * 16 + l_lo) * 520 + kt * 32 + l_hi * 8);
      acc2[m] = __builtin_amdgcn_mfma_f32_16x16x32_bf16(af, bfr, acc2[m], 0, 0, 0);
    }
  }
  {
    const int coln = w * 16 + l_lo;
    const float bias = nb2[coln];
    #pragma unroll
    for (int m = 0; m < 4; m++)
      #pragma unroll
      for (int rr = 0; rr < 4; rr++) {
        const int row = n0 + m * 16 + l_hi * 4 + rr;
        if (row < NN)
          out[(size_t)row * 128 + coln] = h[(size_t)row * 128 + coln] + silu_f(acc2[m][rr] + bias);
      }
  }
}

__global__ void coord_kernel(const float* __restrict__ coord, const float* __restrict__ agg_c,
                             const float* __restrict__ cnt, float* __restrict__ out) {
  int i = blockIdx.x * 256 + threadIdx.x;
  if (i < NN * 9) {
    float cc = fmaxf(cnt[i / 9], 1.f);
    float v = agg_c[i] / cc;
    v = fminf(fmaxf(v, -10.f), 10.f);
    out[i] = coord[i] + v;
  }
}

extern "C" void kernel_launch(void* const* d_in, const int* in_sizes, int n_in,
                              void* d_out, int out_size, void* d_ws, size_t ws_size,
                              hipStream_t stream) {
  (void)in_sizes; (void)n_in; (void)out_size; (void)ws_size;
  const float* h     = (const float*)d_in[0];
  const int*   eidx  = (const int*)d_in[1];
  const float* coord = (const float*)d_in[2];
  const float* eW1 = (const float*)d_in[3];  const float* eb1 = (const float*)d_in[4];
  const float* eW2 = (const float*)d_in[5];  const float* eb2 = (const float*)d_in[6];
  const float* nW1 = (const float*)d_in[7];  const float* nb1 = (const float*)d_in[8];
  const float* nW2 = (const float*)d_in[9];  const float* nb2 = (const float*)d_in[10];
  const float* cW1 = (const float*)d_in[11]; const float* cb1 = (const float*)d_in[12];
  const float* cW2 = (const float*)d_in[13];

  char* ws = (char*)d_ws;
  u16* W1s  = (u16*)(ws + OFF_W1);
  u16* W2s  = (u16*)(ws + OFF_W2);
  u16* WC1s = (u16*)(ws + OFF_WC1);
  u16* WC2s = (u16*)(ws + OFF_WC2);
  u16* WN1s = (u16*)(ws + OFF_WN1);
  u16* WN2s = (u16*)(ws + OFF_WN2);
  u16* hb   = (u16*)(ws + OFF_HB);
  u16* agg_h  = (u16*)(ws + OFF_AGGH);
  float* agg_c = (float*)(ws + OFF_AGGC);
  float* cnt   = (float*)(ws + OFF_CNT);
  float* out   = (float*)d_out;

  hipMemsetAsync(ws + OFF_AGGH, 0, SZ_AGGH + SZ_AGGC + SZ_CNT, stream);

  swz32_kernel<<<18 * 17 * 2, 256, 0, stream>>>(eW1, W1s, 265, 530, 18, 17);
  swz32_kernel<<<34 * 4 * 2, 256, 0, stream>>>(eW2, W2s, 530, 128, 34, 4);
  swz32_kernel<<<8 * 8 * 2, 256, 0, stream>>>(cW1, WC1s, 128, 256, 8, 8);
  swz32_kernel<<<16 * 1 * 2, 256, 0, stream>>>(cW2, WC2s, 256, 3, 16, 1);
  swz_kernel<<<8 * 32 * 2, 256, 0, stream>>>(nW1, WN1s, 256, 512, 8, 32);
  swz_kernel<<<16 * 8 * 2, 256, 0, stream>>>(nW2, WN2s, 512, 128, 16, 8);
  tob16_kernel<<<(NN * 128 + 255) / 256, 256, 0, stream>>>(h, hb, NN * 128);

  edge_kernel<<<NE / 64, 256, 0, stream>>>(hb, eidx, coord, W1s, eb1, W2s, eb2,
                                           WC1s, cb1, WC2s, agg_h, agg_c, cnt);
  node_kernel<<<(NN + 63) / 64, 512, 0, stream>>>(h, hb, agg_h, WN1s, nb1, WN2s, nb2, out);
  coord_kernel<<<(NN * 9 + 255) / 256, 256, 0, stream>>>(coord, agg_c, cnt, out + (size_t)NN * 128);
}

// Round 10
// 376.369 us; speedup vs baseline: 3.0680x; 1.2180x over previous
//
#include <hip/hip_runtime.h>
#include <hip/hip_bf16.h>

typedef unsigned short u16;
typedef __bf16 bf16x8 __attribute__((ext_vector_type(8)));
typedef float f32x4 __attribute__((ext_vector_type(4)));
typedef float f32x16 __attribute__((ext_vector_type(16)));
typedef short v2s __attribute__((ext_vector_type(2)));

#define NN 20000
#define NE 320000

// ---------------- ws layout (bytes) ----------------
constexpr size_t SZ_W1  = (size_t)18 * 17 * 512 * 2;  // eW1: K 288, N 544 (32x32 swz)
constexpr size_t SZ_W2  = (size_t)34 * 4  * 512 * 2;  // eW2: K 544, N 128
constexpr size_t SZ_WC1 = (size_t)8  * 8  * 512 * 2;  // cW1: K 128, N 256
constexpr size_t SZ_WC2 = (size_t)16 * 1  * 512 * 2;  // cW2: K 256, N 32(3)
constexpr size_t SZ_WN1 = (size_t)8  * 32 * 512 * 2;  // nW1 (16x16 swz)
constexpr size_t SZ_WN2 = (size_t)16 * 8  * 512 * 2;  // nW2
constexpr size_t OFF_W1   = 0;
constexpr size_t OFF_W2   = OFF_W1 + SZ_W1;
constexpr size_t OFF_WC1  = OFF_W2 + SZ_W2;
constexpr size_t OFF_WC2  = OFF_WC1 + SZ_WC1;
constexpr size_t OFF_WN1  = OFF_WC2 + SZ_WC2;
constexpr size_t OFF_WN2  = OFF_WN1 + SZ_WN1;
constexpr size_t OFF_HB   = OFF_WN2 + SZ_WN2;         // bf16 [NN,128]
constexpr size_t SZ_HB    = (size_t)NN * 128 * 2;
constexpr size_t OFF_AGGH = OFF_HB + SZ_HB;           // bf16 [NN,128]
constexpr size_t SZ_AGGH  = (size_t)NN * 128 * 2;
constexpr size_t OFF_AGGC = OFF_AGGH + SZ_AGGH;       // f32 [NN,9]
constexpr size_t SZ_AGGC  = (size_t)NN * 9 * 4;
constexpr size_t OFF_CNT  = OFF_AGGC + SZ_AGGC;       // f32 [NN]
constexpr size_t SZ_CNT   = (size_t)NN * 4;

__device__ __forceinline__ u16 f2b(float x) {
  union { float f; unsigned u; } v; v.f = x;
  unsigned r = (v.u + 0x7fffu + ((v.u >> 16) & 1u)) >> 16;
  return (u16)r;
}
__device__ __forceinline__ float b2f(unsigned b) {
  union { unsigned u; float f; } v; v.u = b << 16; return v.f;
}
__device__ __forceinline__ float silu_f(float x) {
  float e = __builtin_amdgcn_exp2f(-1.44269504088896f * x);
  return x * __builtin_amdgcn_rcpf(1.f + e);
}
__device__ __forceinline__ void pk_atomic_bf16(u16* p, float a, float b) {
#if __has_builtin(__builtin_amdgcn_global_atomic_fadd_v2bf16)
  v2s v; v[0] = (short)f2b(a); v[1] = (short)f2b(b);
  __builtin_amdgcn_global_atomic_fadd_v2bf16((v2s*)p, v);
#else
  unsigned* q = (unsigned*)p;
  unsigned old = *q, assumed;
  do {
    assumed = old;
    float lo = b2f(assumed & 0xffffu) + a;
    float hi = b2f(assumed >> 16) + b;
    unsigned nv = (unsigned)f2b(lo) | ((unsigned)f2b(hi) << 16);
    old = atomicCAS(q, assumed, nv);
  } while (old != assumed);
#endif
}
__device__ __forceinline__ f32x16 z16() {
  f32x16 v;
  #pragma unroll
  for (int i = 0; i < 16; i++) v[i] = 0.f;
  return v;
}
__device__ __forceinline__ bf16x8 ldf(const u16* p) {
  return *reinterpret_cast<const bf16x8*>(p);
}
#define MFMA32(A,B,C) __builtin_amdgcn_mfma_f32_32x32x16_bf16((A),(B),(C),0,0,0)

// 16x16 B-fragment swizzle (node kernel weights)
__global__ void swz_kernel(const float* __restrict__ W, u16* __restrict__ dst,
                           int Kreal, int Nreal, int KT, int NT) {
  int idx = blockIdx.x * 256 + threadIdx.x;
  int total = KT * NT * 512;
  if (idx >= total) return;
  int e = idx & 7, l = (idx >> 3) & 63, blk = idx >> 9;
  int kt = blk % KT, nt = blk / KT;
  int k = kt * 32 + ((l >> 4) * 8) + e;
  int n = nt * 16 + (l & 15);
  float v = (k < Kreal && n < Nreal) ? W[(size_t)k * Nreal + n] : 0.f;
  dst[idx] = f2b(v);
}

// 32x32 B-fragment swizzle
__global__ void swz32_kernel(const float* __restrict__ W, u16* __restrict__ dst,
                             int Kreal, int Nreal, int KT, int NT) {
  int idx = blockIdx.x * 256 + threadIdx.x;
  int total = KT * NT * 512;
  if (idx >= total) return;
  int e = idx & 7, l = (idx >> 3) & 63, blk = idx >> 9;
  int kt = blk % KT, nt = blk / KT;
  int k = kt * 16 + ((l >> 5) * 8) + e;
  int n = nt * 32 + (l & 31);
  float v = (k < Kreal && n < Nreal) ? W[(size_t)k * Nreal + n] : 0.f;
  dst[idx] = f2b(v);
}

__global__ void tob16_kernel(const float* __restrict__ x, u16* __restrict__ y, int n) {
  int i = blockIdx.x * 256 + threadIdx.x;
  if (i < n) y[i] = f2b(x[i]);
}

// ---- edge pipeline: M=32, 4 waves, 5 blocks/CU, batch-loaded weight registers ----
__global__ __launch_bounds__(256, 5)
void edge_kernel(const u16* __restrict__ hb, const int* __restrict__ eidx,
                 const float* __restrict__ coord,
                 const u16* __restrict__ W1s, const float* __restrict__ b1,
                 const u16* __restrict__ W2s, const float* __restrict__ b2,
                 const u16* __restrict__ WC1s, const float* __restrict__ bc1,
                 const u16* __restrict__ WC2s,
                 u16* __restrict__ agg_h, float* __restrict__ agg_c,
                 float* __restrict__ cnt) {
  __shared__ __align__(16) u16 bufA[32 * 296];  // A1 [32][288+8] -> Y3 [32][264]
  __shared__ __align__(16) u16 bufB[32 * 136];  // Y1 chunk [32][128+8] -> ef [32][136]
  __shared__ float phi_s[32][4];
  __shared__ int row_s[32];

  const int tid = threadIdx.x;
  const int lane = tid & 63;
  const int nh = tid >> 6;
  const int l5 = lane & 31;
  const int hi = lane >> 5;
  const int e0 = blockIdx.x << 5;

  // gather h (all waves) + radial (tid<32)
  for (int q = tid; q < 1024; q += 256) {
    const int e = q >> 5, sub = q & 31, which = sub >> 4, j = sub & 15;
    const int node = eidx[(which ? NE : 0) + e0 + e];
    const int4 v = *reinterpret_cast<const int4*>(hb + (size_t)node * 128 + j * 8);
    *reinterpret_cast<int4*>(bufA + e * 296 + which * 128 + j * 8) = v;
  }
  if (tid < 32) {
    const int r = eidx[e0 + tid], c = eidx[NE + e0 + tid];
    row_s[tid] = r;
    float cd[9];
    #pragma unroll
    for (int i = 0; i < 9; i++) cd[i] = coord[r * 9 + i] - coord[c * 9 + i];
    u16* arow = bufA + tid * 296;
    #pragma unroll
    for (int a = 0; a < 3; a++)
      #pragma unroll
      for (int b = 0; b < 3; b++) {
        float rad = cd[a*3]*cd[b*3] + cd[a*3+1]*cd[b*3+1] + cd[a*3+2]*cd[b*3+2];
        arow[256 + a * 3 + b] = f2b(rad);
      }
    #pragma unroll
    for (int k = 265; k < 288; k++) arow[k] = (u16)0;
  }
  __syncthreads();  // A1 + row_s ready

  // ---- chunked GEMM1 [32,288]x[288,544] -> silu -> GEMM2 [32,544]x[544,128] ----
  f32x16 acc2 = z16();

  #pragma unroll
  for (int c = 0; c < 5; c++) {
    const int nt = c * 4 + nh;
    const bool act = (nt < 17);
    f32x16 acc1 = z16();

    if (act) {
      // batch-loaded weights: 3 batches of 6 fragments, loads issued in
      // dedicated loops (static indices, no interleaved uses) so they stay
      // grouped -> one latency exposure per batch instead of per load.
      const u16* wp = W1s + (((nt * 18) << 6) + lane) * 8;
      const u16* ap = bufA + l5 * 296 + hi * 8;
      bf16x8 w0[6], w1[6], w2[6];
      #pragma unroll
      for (int j = 0; j < 6; j++) w0[j] = ldf(wp + j * 512);
      #pragma unroll
      for (int j = 0; j < 6; j++) w1[j] = ldf(wp + (6 + j) * 512);
      #pragma unroll
      for (int j = 0; j < 6; j++)
        acc1 = MFMA32(ldf(ap + j * 16), w0[j], acc1);
      #pragma unroll
      for (int j = 0; j < 6; j++) w2[j] = ldf(wp + (12 + j) * 512);
      #pragma unroll
      for (int j = 0; j < 6; j++)
        acc1 = MFMA32(ldf(ap + (6 + j) * 16), w1[j], acc1);
      #pragma unroll
      for (int j = 0; j < 6; j++)
        acc1 = MFMA32(ldf(ap + (12 + j) * 16), w2[j], acc1);
    }
    __syncthreads();  // prev chunk's GEMM2 reads of bufB complete
    if (act) {
      const int colg = nt * 32 + l5;
      const float bias = (colg < 530) ? b1[colg] : 0.f;
      const int coll = nh * 32 + l5;
      #pragma unroll
      for (int r = 0; r < 16; r++) {
        const int rowi = (r & 3) + 8 * (r >> 2) + 4 * hi;
        bufB[rowi * 136 + coll] = f2b(silu_f(acc1[r] + bias));
      }
    }
    __syncthreads();  // Y1 chunk ready

    const u16* bp = bufB + l5 * 136 + hi * 8;
    if (c < 4) {
      const u16* wp2 = W2s + (((nh * 34 + c * 8) << 6) + lane) * 8;
      bf16x8 wa[4], wb[4];
      #pragma unroll
      for (int j = 0; j < 4; j++) wa[j] = ldf(wp2 + j * 512);
      #pragma unroll
      for (int j = 0; j < 4; j++) wb[j] = ldf(wp2 + (4 + j) * 512);
      #pragma unroll
      for (int j = 0; j < 4; j++)
        acc2 = MFMA32(ldf(bp + j * 16), wa[j], acc2);
      #pragma unroll
      for (int j = 0; j < 4; j++)
        acc2 = MFMA32(ldf(bp + (4 + j) * 16), wb[j], acc2);
    } else {
      const u16* wp2 = W2s + (((nh * 34 + 32) << 6) + lane) * 8;
      bf16x8 wa[2];
      wa[0] = ldf(wp2);
      wa[1] = ldf(wp2 + 512);
      acc2 = MFMA32(ldf(bp), wa[0], acc2);
      acc2 = MFMA32(ldf(bp + 16), wa[1], acc2);
    }
  }
  __syncthreads();  // all GEMM2 reads of bufB done

  // ef = silu(acc2 + b2): keep in regs, write bf16 to bufB [32][136]
  f32x16 efv;
  {
    const int col = nh * 32 + l5;
    const float bias = b2[col];
    #pragma unroll
    for (int r = 0; r < 16; r++) {
      const int rowi = (r & 3) + 8 * (r >> 2) + 4 * hi;
      efv[r] = silu_f(acc2[r] + bias);
      bufB[rowi * 136 + col] = f2b(efv[r]);
    }
  }
  __syncthreads();  // ef ready

  // GEMM3: ef[32,128] x WC1[128,256]; wave nh: n-tiles nh*2+{0,1}; halves of kt
  f32x16 acc3[2];
  #pragma unroll
  for (int i = 0; i < 2; i++) acc3[i] = z16();
  {
    const u16* wpa = WC1s + ((((nh * 2) * 8) << 6) + lane) * 8;
    const u16* wpb = wpa + 8 * 512;
    const u16* bp = bufB + l5 * 136 + hi * 8;
    bf16x8 wa[4], wb[4];
    #pragma unroll
    for (int j = 0; j < 4; j++) wa[j] = ldf(wpa + j * 512);
    #pragma unroll
    for (int j = 0; j < 4; j++) wb[j] = ldf(wpb + j * 512);
    #pragma unroll
    for (int j = 0; j < 4; j++) {
      const bf16x8 a = ldf(bp + j * 16);
      acc3[0] = MFMA32(a, wa[j], acc3[0]);
      acc3[1] = MFMA32(a, wb[j], acc3[1]);
    }
    #pragma unroll
    for (int j = 0; j < 4; j++) wa[j] = ldf(wpa + (4 + j) * 512);
    #pragma unroll
    for (int j = 0; j < 4; j++) wb[j] = ldf(wpb + (4 + j) * 512);
    #pragma unroll
    for (int j = 0; j < 4; j++) {
      const bf16x8 a = ldf(bp + (4 + j) * 16);
      acc3[0] = MFMA32(a, wa[j], acc3[0]);
      acc3[1] = MFMA32(a, wb[j], acc3[1]);
    }
  }

  // agg_h packed-bf16 atomics (drain hides under epi3)
  {
    const int col = nh * 32 + l5;
    #pragma unroll
    for (int r = 0; r < 16; r++) {
      const float other = __shfl_xor(efv[r], 1);
      if ((l5 & 1) == 0) {
        const int rowi = (r & 3) + 8 * (r >> 2) + 4 * hi;
        pk_atomic_bf16(agg_h + (size_t)row_s[rowi] * 128 + col, efv[r], other);
      }
    }
  }

  // epi3 -> bufA as Y3 [32][264]
  #pragma unroll
  for (int i = 0; i < 2; i++) {
    const int col = (nh * 2 + i) * 32 + l5;
    const float bias = bc1[col];
    #pragma unroll
    for (int r = 0; r < 16; r++) {
      const int rowi = (r & 3) + 8 * (r >> 2) + 4 * hi;
      bufA[rowi * 264 + col] = f2b(silu_f(acc3[i][r] + bias));
    }
  }
  __syncthreads();  // Y3 ready

  // GEMM4 (wave 0 only): Y3[32,256] x WC2[256,32(3)]; halves of 8
  if (nh == 0) {
    f32x16 acc4 = z16();
    const u16* wp4 = WC2s + lane * 8;
    const u16* ap = bufA + l5 * 264 + hi * 8;
    bf16x8 wq[8];
    #pragma unroll
    for (int j = 0; j < 8; j++) wq[j] = ldf(wp4 + j * 512);
    #pragma unroll
    for (int j = 0; j < 8; j++)
      acc4 = MFMA32(ldf(ap + j * 16), wq[j], acc4);
    #pragma unroll
    for (int j = 0; j < 8; j++) wq[j] = ldf(wp4 + (8 + j) * 512);
    #pragma unroll
    for (int j = 0; j < 8; j++)
      acc4 = MFMA32(ldf(ap + (8 + j) * 16), wq[j], acc4);
    if (l5 < 3) {
      #pragma unroll
      for (int r = 0; r < 16; r++)
        phi_s[(r & 3) + 8 * (r >> 2) + 4 * hi][l5] = acc4[r];
    }
    // wave-internal LDS handoff (compiler inserts lgkmcnt wait)
    if (lane < 32) {
      const int r = row_s[lane], ci = eidx[NE + e0 + lane];
      float cd[9];
      #pragma unroll
      for (int i = 0; i < 9; i++) cd[i] = coord[r * 9 + i] - coord[ci * 9 + i];
      const float p0 = phi_s[lane][0], p1 = phi_s[lane][1], p2 = phi_s[lane][2];
      float* gc = agg_c + (size_t)r * 9;
      #pragma unroll
      for (int d = 0; d < 3; d++) {
        atomicAdd(gc + d,     cd[d]     * p0);
        atomicAdd(gc + 3 + d, cd[3 + d] * p1);
        atomicAdd(gc + 6 + d, cd[6 + d] * p2);
      }
      atomicAdd(cnt + r, 1.f);
    }
  }
}

// ---------------- node MLP (16x16 path; agg_h bf16) ----------------
__global__ __launch_bounds__(512)
void node_kernel(const float* __restrict__ h, const u16* __restrict__ hb,
                 const u16* __restrict__ aggh,
                 const u16* __restrict__ WN1s, const float* __restrict__ nb1,
                 const u16* __restrict__ WN2s, const float* __restrict__ nb2,
                 float* __restrict__ out) {
  __shared__ __align__(16) u16 buf[64 * 520];
  const int tid = threadIdx.x;
  const int lane = tid & 63;
  const int w = tid >> 6;
  const int l_lo = lane & 15;
  const int l_hi = lane >> 4;
  const int n0 = blockIdx.x << 6;

  for (int q = tid; q < 2048; q += 512) {
    const int e = q >> 5, sub = q & 31, which = sub >> 4, j = sub & 15;
    const int row = n0 + e;
    const u16* src = which ? aggh : hb;
    int4 v;
    if (row < NN) v = *reinterpret_cast<const int4*>(src + (size_t)row * 128 + j * 8);
    else { v.x = v.y = v.z = v.w = 0; }
    *reinterpret_cast<int4*>(buf + e * 264 + which * 128 + j * 8) = v;
  }
  __syncthreads();

  f32x4 acc[4][4];
  #pragma unroll
  for (int i = 0; i < 4; i++)
    #pragma unroll
    for (int m = 0; m < 4; m++) acc[i][m] = {0.f, 0.f, 0.f, 0.f};
  for (int kt = 0; kt < 8; kt++) {
    bf16x8 af[4];
    #pragma unroll
    for (int m = 0; m < 4; m++)
      af[m] = *reinterpret_cast<const bf16x8*>(buf + (m * 16 + l_lo) * 264 + kt * 32 + l_hi * 8);
    #pragma unroll
    for (int i = 0; i < 4; i++) {
      const int nt = w + 8 * i;
      const bf16x8 bfr = *reinterpret_cast<const bf16x8*>(WN1s + (((nt * 8 + kt) << 6) + lane) * 8);
      #pragma unroll
      for (int m = 0; m < 4; m++)
        acc[i][m] = __builtin_amdgcn_mfma_f32_16x16x32_bf16(af[m], bfr, acc[i][m], 0, 0, 0);
    }
  }
  __syncthreads();
  #pragma unroll
  for (int i = 0; i < 4; i++) {
    const int nt = w + 8 * i;
    const int coln = nt * 16 + l_lo;
    const float bias = nb1[coln];
    #pragma unroll
    for (int m = 0; m < 4; m++)
      #pragma unroll
      for (int rr = 0; rr < 4; rr++) {
        const int row = m * 16 + l_hi * 4 + rr;
        buf[row * 520 + coln] = f2b(silu_f(acc[i][m][rr] + bias));
      }
  }
  __syncthreads();

  f32x4 acc2[4];
  #pragma unroll
  for (int m = 0; m < 4; m++) acc2[m] = {0.f, 0.f, 0.f, 0.f};
  for (int kt = 0; kt < 16; kt++) {
    const bf16x8 bfr = *reinterpret_cast<const bf16x8*>(WN2s + (((w * 16 + kt) << 6) + lane) * 8);
    #pragma unroll
    for (int m = 0; m < 4; m++) {
      const bf16x8 af = *reinterpret_cast<const bf16x8*>(buf + (m * 16 + l_lo) * 520 + kt * 32 + l_hi * 8);
      acc2[m] = __builtin_amdgcn_mfma_f32_16x16x32_bf16(af, bfr, acc2[m], 0, 0, 0);
    }
  }
  {
    const int coln = w * 16 + l_lo;
    const float bias = nb2[coln];
    #pragma unroll
    for (int m = 0; m < 4; m++)
      #pragma unroll
      for (int rr = 0; rr < 4; rr++) {
        const int row = n0 + m * 16 + l_hi * 4 + rr;
        if (row < NN)
          out[(size_t)row * 128 + coln] = h[(size_t)row * 128 + coln] + silu_f(acc2[m][rr] + bias);
      }
  }
}

__global__ void coord_kernel(const float* __restrict__ coord, const float* __restrict__ agg_c,
                             const float* __restrict__ cnt, float* __restrict__ out) {
  int i = blockIdx.x * 256 + threadIdx.x;
  if (i < NN * 9) {
    float cc = fmaxf(cnt[i / 9], 1.f);
    float v = agg_c[i] / cc;
    v = fminf(fmaxf(v, -10.f), 10.f);
    out[i] = coord[i] + v;
  }
}

extern "C" void kernel_launch(void* const* d_in, const int* in_sizes, int n_in,
                              void* d_out, int out_size, void* d_ws, size_t ws_size,
                              hipStream_t stream) {
  (void)in_sizes; (void)n_in; (void)out_size; (void)ws_size;
  const float* h     = (const float*)d_in[0];
  const int*   eidx  = (const int*)d_in[1];
  const float* coord = (const float*)d_in[2];
  const float* eW1 = (const float*)d_in[3];  const float* eb1 = (const float*)d_in[4];
  const float* eW2 = (const float*)d_in[5];  const float* eb2 = (const float*)d_in[6];
  const float* nW1 = (const float*)d_in[7];  const float* nb1 = (const float*)d_in[8];
  const float* nW2 = (const float*)d_in[9];  const float* nb2 = (const float*)d_in[10];
  const float* cW1 = (const float*)d_in[11]; const float* cb1 = (const float*)d_in[12];
  const float* cW2 = (const float*)d_in[13];

  char* ws = (char*)d_ws;
  u16* W1s  = (u16*)(ws + OFF_W1);
  u16* W2s  = (u16*)(ws + OFF_W2);
  u16* WC1s = (u16*)(ws + OFF_WC1);
  u16* WC2s = (u16*)(ws + OFF_WC2);
  u16* WN1s = (u16*)(ws + OFF_WN1);
  u16* WN2s = (u16*)(ws + OFF_WN2);
  u16* hb   = (u16*)(ws + OFF_HB);
  u16* agg_h  = (u16*)(ws + OFF_AGGH);
  float* agg_c = (float*)(ws + OFF_AGGC);
  float* cnt   = (float*)(ws + OFF_CNT);
  float* out   = (float*)d_out;

  hipMemsetAsync(ws + OFF_AGGH, 0, SZ_AGGH + SZ_AGGC + SZ_CNT, stream);

  swz32_kernel<<<18 * 17 * 2, 256, 0, stream>>>(eW1, W1s, 265, 530, 18, 17);
  swz32_kernel<<<34 * 4 * 2, 256, 0, stream>>>(eW2, W2s, 530, 128, 34, 4);
  swz32_kernel<<<8 * 8 * 2, 256, 0, stream>>>(cW1, WC1s, 128, 256, 8, 8);
  swz32_kernel<<<16 * 1 * 2, 256, 0, stream>>>(cW2, WC2s, 256, 3, 16, 1);
  swz_kernel<<<8 * 32 * 2, 256, 0, stream>>>(nW1, WN1s, 256, 512, 8, 32);
  swz_kernel<<<16 * 8 * 2, 256, 0, stream>>>(nW2, WN2s, 512, 128, 16, 8);
  tob16_kernel<<<(NN * 128 + 255) / 256, 256, 0, stream>>>(h, hb, NN * 128);

  edge_kernel<<<NE / 32, 256, 0, stream>>>(hb, eidx, coord, W1s, eb1, W2s, eb2,
                                           WC1s, cb1, WC2s, agg_h, agg_c, cnt);
  node_kernel<<<(NN + 63) / 64, 512, 0, stream>>>(h, hb, agg_h, WN1s, nb1, WN2s, nb2, out);
  coord_kernel<<<(NN * 9 + 255) / 256, 256, 0, stream>>>(coord, agg_c, cnt, out + (size_t)NN * 128);
}